// Round 4
// baseline (329.827 us; speedup 1.0000x reference)
//
#include <hip/hip_runtime.h>
#include <hip/hip_bf16.h>
#include <cstdint>

// LSTM cell: B=8192, I=1024, H=1024.
// gates = [x|h] @ [Wf|Wi|Wc|Wo] + b ; fused elementwise gate combine.
// R4: GEMM switched to 32x32x16 bf16 MFMA (2495 vs 2176 TF pipe rate, half
// the MFMA issue count). Wave = 32-row band x 128 n-cols (4 gate tiles) so
// gates remain lane-local for the fused epilogue. Staging + XOR swizzle
// unchanged from R2/R3 (0 bank conflicts). Packs merged into one launch.

#define BROWS 8192
#define IH    2048
#define HDIM  1024

typedef __bf16 bf16x4 __attribute__((ext_vector_type(4)));
typedef __bf16 bf16x8 __attribute__((ext_vector_type(8)));
typedef float  f32x16 __attribute__((ext_vector_type(16)));

// ---------------------------------------------------------------- pack_both
// Blocks [0,8192):      A_bf16[row][2048] = bf16([x_row | h_row])
// Blocks [8192,16384):  Wt[g*1024+n][k] = bf16(W_g[k][n]) via 32x32 LDS tile
__global__ void pack_both(const float* __restrict__ x, const float* __restrict__ hs,
                          const float* __restrict__ Wf, const float* __restrict__ Wi,
                          const float* __restrict__ Wc, const float* __restrict__ Wo,
                          __bf16* __restrict__ A, __bf16* __restrict__ Wt) {
    __shared__ float tile[32][33];            // 4.2 KiB — no occupancy cap
    const int tid = threadIdx.x;
    if (blockIdx.x < 8192) {
        // ---- A pack: one A-row per block; no per-lane branch
        const int row = blockIdx.x;
        const float4 vx = *(const float4*)(x  + (size_t)row * 1024 + tid * 4);
        const float4 vh = *(const float4*)(hs + (size_t)row * 1024 + tid * 4);
        bf16x4 rx, rh;
        rx[0]=(__bf16)vx.x; rx[1]=(__bf16)vx.y; rx[2]=(__bf16)vx.z; rx[3]=(__bf16)vx.w;
        rh[0]=(__bf16)vh.x; rh[1]=(__bf16)vh.y; rh[2]=(__bf16)vh.z; rh[3]=(__bf16)vh.w;
        __bf16* dst = A + (size_t)row * 2048;
        *(bf16x4*)(dst + tid * 4)        = rx;
        *(bf16x4*)(dst + 1024 + tid * 4) = rh;
    } else {
        // ---- W transpose+cast: 32x32 tile
        int b = blockIdx.x - 8192;
        const int g = b & 3; b >>= 2;
        const int n0 = (b & 31) * 32;
        const int k0 = (b >> 5) * 32;
        const float* W = (g == 0) ? Wf : (g == 1) ? Wi : (g == 2) ? Wc : Wo;
        {   // phase 1: 256 threads x 1 float4 = 32x32 floats
            const int k = tid >> 3, c = tid & 7;
            *(float4*)&tile[k][c * 4] = *(const float4*)&W[(size_t)(k0 + k) * HDIM + n0 + c * 4];
        }
        __syncthreads();
        {   // phase 2: (n = tid>>3, kq = tid&7), 4 k's each; 2-way LDS = free
            const int n = tid >> 3, kq = tid & 7;
            bf16x4 r;
#pragma unroll
            for (int j = 0; j < 4; ++j) r[j] = (__bf16)tile[kq * 4 + j][n];
            *(bf16x4*)&Wt[(size_t)(g * HDIM + n0 + n) * IH + k0 + kq * 4] = r;
        }
    }
}

// ---------------------------------------------------------------- lstm_gemm
// Block: 256 threads (4 waves). BM=128 rows x (4 gates x 32 h) = 128x128.
// BK=64. 32x32x16 bf16 MFMA. Wave w owns rows [w*32, w*32+32) x all 128 n.
// LDS XOR swizzle: logical 16B chunk jc of row r at physical jc^(r&7).
#define BM 128
#define BH 32
#define BK 64

__global__ void lstm_gemm(const __bf16* __restrict__ A,    // [8192][2048]
                          const __bf16* __restrict__ Wt,   // [4096][2048], row g*1024+h
                          const float* __restrict__ cell,  // [8192][1024]
                          const float* __restrict__ bF_, const float* __restrict__ bI_,
                          const float* __restrict__ bC_, const float* __restrict__ bO_,
                          float* __restrict__ out)         // [2][8192][1024]
{
    __shared__ __bf16 As[BM * BK];            // [128 m][64 k], swizzled chunks
    __shared__ __bf16 Bs[4 * BH * BK];        // [128 n][64 k], n = g*32 + hl

    const int tid   = threadIdx.x;
    const int wave  = tid >> 6;               // 0..3 : 32-row band
    const int lane  = tid & 63;
    const int n32   = lane & 31;              // m (A-frag) / n (B-frag) in tile
    const int khalf = lane >> 5;              // 0..1 : k-group selector
    const int sw    = lane & 7;               // swizzle key = row&7 for frag rows

    const int m0 = blockIdx.y * BM;
    const int h0 = blockIdx.x * BH;

    const int lrow = lane >> 3;               // staging row 0..7
    const int lk   = (((lane & 7) ^ (lrow & 7)) << 3);  // swizzled elem offset

    f32x16 acc[4] = {};                       // [gate]

    for (int k0 = 0; k0 < IH; k0 += BK) {
        // ---- stage A tile (identical to R2/R3)
#pragma unroll
        for (int i = 0; i < 4; ++i) {
            int c = wave * 4 + i;
            int row = c * 8 + lrow;
            const __bf16* gp = A + (size_t)(m0 + row) * IH + k0 + lk;
            __bf16* lp = &As[c * 8 * BK];
            __builtin_amdgcn_global_load_lds(
                (const __attribute__((address_space(1))) unsigned*)gp,
                (__attribute__((address_space(3))) unsigned*)lp, 16, 0, 0);
        }
        // ---- stage B tile (identical to R2/R3)
#pragma unroll
        for (int i = 0; i < 4; ++i) {
            int c = wave * 4 + i;
            int rl = c * 8 + lrow;
            int g = rl >> 5, hl = rl & 31;
            const __bf16* gp = Wt + (size_t)(g * HDIM + h0 + hl) * IH + k0 + lk;
            __bf16* lp = &Bs[c * 8 * BK];
            __builtin_amdgcn_global_load_lds(
                (const __attribute__((address_space(1))) unsigned*)gp,
                (__attribute__((address_space(3))) unsigned*)lp, 16, 0, 0);
        }
        __syncthreads();

        // ---- 4 k-steps of 16; per step: 1 A-frag read, 4 B-frag reads, 4 MFMA
#pragma unroll
        for (int ks = 0; ks < 4; ++ks) {
            const int ch = (ks * 2 + khalf) ^ sw;       // physical chunk
            bf16x8 af = *(const bf16x8*)&As[(wave * 32 + n32) * BK + (ch << 3)];
            bf16x8 bg[4];
#pragma unroll
            for (int g = 0; g < 4; ++g)
                bg[g] = *(const bf16x8*)&Bs[(g * 32 + n32) * BK + (ch << 3)];
#pragma unroll
            for (int g = 0; g < 4; ++g)
                acc[g] = __builtin_amdgcn_mfma_f32_32x32x16_bf16(af, bg[g], acc[g], 0, 0, 0);
        }
        __syncthreads();
    }

    // ---- fused epilogue: C layout col=lane&31, row=(reg&3)+8*(reg>>2)+4*khalf
    const int h = h0 + n32;
    const float bF = bF_[h], bI = bI_[h], bC = bC_[h], bO = bO_[h];
#pragma unroll
    for (int reg = 0; reg < 16; ++reg) {
        const int ri = (reg & 3) + 8 * (reg >> 2) + 4 * khalf;
        const int m  = m0 + wave * 32 + ri;
        float pf = acc[0][reg] + bF;
        float pi = acc[1][reg] + bI;
        float pc = acc[2][reg] + bC;
        float po = acc[3][reg] + bO;
        float f  = 1.f / (1.f + __expf(-pf));
        float ig = 1.f / (1.f + __expf(-pi));
        float og = 1.f / (1.f + __expf(-po));
        float e2 = __expf(2.f * pc);
        float cd = (e2 - 1.f) / (e2 + 1.f);            // tanh(pc)
        float cp = cell[(size_t)m * HDIM + h];
        float cn = f * cp + ig * cd;
        float ec = __expf(2.f * cn);
        float tc = (ec - 1.f) / (ec + 1.f);            // tanh(cn)
        out[(size_t)m * HDIM + h] = og * tc;                       // new_hidden
        out[(size_t)BROWS * HDIM + (size_t)m * HDIM + h] = cn;     // new_cell
    }
}

// ---------------------------------------------------------------- launch
extern "C" void kernel_launch(void* const* d_in, const int* in_sizes, int n_in,
                              void* d_out, int out_size, void* d_ws, size_t ws_size,
                              hipStream_t stream) {
    const float* x  = (const float*)d_in[0];
    const float* hs = (const float*)d_in[1];
    const float* cs = (const float*)d_in[2];
    const float* Wf = (const float*)d_in[3];
    const float* bF = (const float*)d_in[4];
    const float* Wi = (const float*)d_in[5];
    const float* bI = (const float*)d_in[6];
    const float* Wc = (const float*)d_in[7];
    const float* bC = (const float*)d_in[8];
    const float* Wo = (const float*)d_in[9];
    const float* bO = (const float*)d_in[10];
    float* out = (float*)d_out;

    __bf16* A  = (__bf16*)d_ws;                                   // 32 MiB
    __bf16* Wt = (__bf16*)((char*)d_ws + (size_t)BROWS * IH * 2); // 16 MiB

    pack_both<<<8192 + 8192, 256, 0, stream>>>(x, hs, Wf, Wi, Wc, Wo, A, Wt);
    lstm_gemm<<<dim3(HDIM / BH, BROWS / BM), 256, 0, stream>>>(A, Wt, cs, bF, bI, bC, bO, out);
}

// Round 5
// 322.344 us; speedup vs baseline: 1.0232x; 1.0232x over previous
//
#include <hip/hip_runtime.h>
#include <hip/hip_bf16.h>
#include <cstdint>

// LSTM cell: B=8192, I=1024, H=1024.
// gates = [x|h] @ [Wf|Wi|Wc|Wo] + b ; fused elementwise gate combine.
// R5: LDS-bandwidth model. R2's 910TF plateau = LDS-BW bound (96KB LDS
// traffic / 2.1 MFLOP per block-k-iter). Fix: register blocking — wave owns
// 64 rows x 128 cols => 6 frag reads per 8 mfma_32x32x16 (0.75 reads/MFMA),
// block tile 256x128, 17KB/MFLOP LDS traffic. MFMA pipe becomes the limit.

#define BROWS 8192
#define IH    2048
#define HDIM  1024

typedef __bf16 bf16x4 __attribute__((ext_vector_type(4)));
typedef __bf16 bf16x8 __attribute__((ext_vector_type(8)));
typedef float  f32x16 __attribute__((ext_vector_type(16)));

// ---------------------------------------------------------------- pack_both
// Blocks [0,8192):      A_bf16[row][2048] = bf16([x_row | h_row])
// Blocks [8192,16384):  Wt[g*1024+n][k] = bf16(W_g[k][n]) via 32x32 LDS tile
__global__ void pack_both(const float* __restrict__ x, const float* __restrict__ hs,
                          const float* __restrict__ Wf, const float* __restrict__ Wi,
                          const float* __restrict__ Wc, const float* __restrict__ Wo,
                          __bf16* __restrict__ A, __bf16* __restrict__ Wt) {
    __shared__ float tile[32][33];
    const int tid = threadIdx.x;
    if (blockIdx.x < 8192) {
        const int row = blockIdx.x;
        const float4 vx = *(const float4*)(x  + (size_t)row * 1024 + tid * 4);
        const float4 vh = *(const float4*)(hs + (size_t)row * 1024 + tid * 4);
        bf16x4 rx, rh;
        rx[0]=(__bf16)vx.x; rx[1]=(__bf16)vx.y; rx[2]=(__bf16)vx.z; rx[3]=(__bf16)vx.w;
        rh[0]=(__bf16)vh.x; rh[1]=(__bf16)vh.y; rh[2]=(__bf16)vh.z; rh[3]=(__bf16)vh.w;
        __bf16* dst = A + (size_t)row * 2048;
        *(bf16x4*)(dst + tid * 4)        = rx;
        *(bf16x4*)(dst + 1024 + tid * 4) = rh;
    } else {
        int b = blockIdx.x - 8192;
        const int g = b & 3; b >>= 2;
        const int n0 = (b & 31) * 32;
        const int k0 = (b >> 5) * 32;
        const float* W = (g == 0) ? Wf : (g == 1) ? Wi : (g == 2) ? Wc : Wo;
        {   // phase 1: 256 threads x 1 float4 = 32x32 floats
            const int k = tid >> 3, c = tid & 7;
            *(float4*)&tile[k][c * 4] = *(const float4*)&W[(size_t)(k0 + k) * HDIM + n0 + c * 4];
        }
        __syncthreads();
        {   // phase 2: 2-way LDS column reads (free), 8B stores
            const int n = tid >> 3, kq = tid & 7;
            bf16x4 r;
#pragma unroll
            for (int j = 0; j < 4; ++j) r[j] = (__bf16)tile[kq * 4 + j][n];
            *(bf16x4*)&Wt[(size_t)(g * HDIM + n0 + n) * IH + k0 + kq * 4] = r;
        }
    }
}

// ---------------------------------------------------------------- lstm_gemm
// Block: 256 threads (4 waves). Tile: BM=256 rows x (4 gates x 32 h) = 256x128.
// Wave w: rows [w*64, w*64+64) (2 m-tiles of 32) x all 128 n (4 gate-tiles).
// BK=64, 32x32x16 bf16 MFMA, acc[2][4] (128 VGPRs).
// LDS XOR swizzle: logical 16B chunk jc of row r at physical jc^(r&7).
#define BM 256
#define BH 32
#define BK 64

__global__ void __launch_bounds__(256, 2)
lstm_gemm(const __bf16* __restrict__ A,    // [8192][2048]
          const __bf16* __restrict__ Wt,   // [4096][2048], row g*1024+h
          const float* __restrict__ cell,  // [8192][1024]
          const float* __restrict__ bF_, const float* __restrict__ bI_,
          const float* __restrict__ bC_, const float* __restrict__ bO_,
          float* __restrict__ out)         // [2][8192][1024]
{
    __shared__ __bf16 As[BM * BK];            // [256 m][64 k], swizzled chunks, 32KB
    __shared__ __bf16 Bs[4 * BH * BK];        // [128 n][64 k], n = g*32+hl, 16KB

    const int tid   = threadIdx.x;
    const int wave  = tid >> 6;               // 0..3 : 64-row band
    const int lane  = tid & 63;
    const int n32   = lane & 31;              // m/n index within 32-tile
    const int khalf = lane >> 5;              // 0..1 : k-group selector
    const int sw    = lane & 7;               // swizzle key (= frag row & 7)

    const int m0 = blockIdx.y * BM;
    const int h0 = blockIdx.x * BH;

    const int lrow = lane >> 3;               // staging row 0..7
    const int lk   = (((lane & 7) ^ (lrow & 7)) << 3);  // swizzled elem offset

    f32x16 acc[2][4] = {};                    // [mtile][gate]

    for (int k0 = 0; k0 < IH; k0 += BK) {
        // ---- stage A tile: 32 chunks of 8 rows; wave w does chunks w*8+i
#pragma unroll
        for (int i = 0; i < 8; ++i) {
            int c = wave * 8 + i;
            int row = c * 8 + lrow;
            const __bf16* gp = A + (size_t)(m0 + row) * IH + k0 + lk;
            __bf16* lp = &As[c * 8 * BK];
            __builtin_amdgcn_global_load_lds(
                (const __attribute__((address_space(1))) unsigned*)gp,
                (__attribute__((address_space(3))) unsigned*)lp, 16, 0, 0);
        }
        // ---- stage B tile: 16 chunks; wave w does chunks w*4+i
#pragma unroll
        for (int i = 0; i < 4; ++i) {
            int c = wave * 4 + i;
            int rl = c * 8 + lrow;            // 0..127
            int g = rl >> 5, hl = rl & 31;
            const __bf16* gp = Wt + (size_t)(g * HDIM + h0 + hl) * IH + k0 + lk;
            __bf16* lp = &Bs[c * 8 * BK];
            __builtin_amdgcn_global_load_lds(
                (const __attribute__((address_space(1))) unsigned*)gp,
                (__attribute__((address_space(3))) unsigned*)lp, 16, 0, 0);
        }
        __syncthreads();

        // ---- 4 k-steps of 16: per step 2 A-reads + 4 B-reads feed 8 MFMAs
#pragma unroll
        for (int ks = 0; ks < 4; ++ks) {
            const int ch = (ks * 2 + khalf) ^ sw;       // physical chunk
            bf16x8 af[2], bg[4];
#pragma unroll
            for (int mt = 0; mt < 2; ++mt)
                af[mt] = *(const bf16x8*)&As[(wave * 64 + mt * 32 + n32) * BK + (ch << 3)];
#pragma unroll
            for (int g = 0; g < 4; ++g)
                bg[g] = *(const bf16x8*)&Bs[(g * 32 + n32) * BK + (ch << 3)];
#pragma unroll
            for (int mt = 0; mt < 2; ++mt)
#pragma unroll
                for (int g = 0; g < 4; ++g)
                    acc[mt][g] = __builtin_amdgcn_mfma_f32_32x32x16_bf16(
                        af[mt], bg[g], acc[mt][g], 0, 0, 0);
        }
        __syncthreads();
    }

    // ---- fused epilogue: C layout col=lane&31, row=(reg&3)+8*(reg>>2)+4*khalf
    const int h = h0 + n32;
    const float bF = bF_[h], bI = bI_[h], bC = bC_[h], bO = bO_[h];
#pragma unroll
    for (int mt = 0; mt < 2; ++mt) {
#pragma unroll
        for (int reg = 0; reg < 16; ++reg) {
            const int ri = (reg & 3) + 8 * (reg >> 2) + 4 * khalf;
            const int m  = m0 + wave * 64 + mt * 32 + ri;
            float pf = acc[mt][0][reg] + bF;
            float pi = acc[mt][1][reg] + bI;
            float pc = acc[mt][2][reg] + bC;
            float po = acc[mt][3][reg] + bO;
            float f  = 1.f / (1.f + __expf(-pf));
            float ig = 1.f / (1.f + __expf(-pi));
            float og = 1.f / (1.f + __expf(-po));
            float e2 = __expf(2.f * pc);
            float cd = (e2 - 1.f) / (e2 + 1.f);          // tanh(pc)
            float cp = cell[(size_t)m * HDIM + h];
            float cn = f * cp + ig * cd;
            float ec = __expf(2.f * cn);
            float tc = (ec - 1.f) / (ec + 1.f);          // tanh(cn)
            out[(size_t)m * HDIM + h] = og * tc;                       // new_hidden
            out[(size_t)BROWS * HDIM + (size_t)m * HDIM + h] = cn;     // new_cell
        }
    }
}

// ---------------------------------------------------------------- launch
extern "C" void kernel_launch(void* const* d_in, const int* in_sizes, int n_in,
                              void* d_out, int out_size, void* d_ws, size_t ws_size,
                              hipStream_t stream) {
    const float* x  = (const float*)d_in[0];
    const float* hs = (const float*)d_in[1];
    const float* cs = (const float*)d_in[2];
    const float* Wf = (const float*)d_in[3];
    const float* bF = (const float*)d_in[4];
    const float* Wi = (const float*)d_in[5];
    const float* bI = (const float*)d_in[6];
    const float* Wc = (const float*)d_in[7];
    const float* bC = (const float*)d_in[8];
    const float* Wo = (const float*)d_in[9];
    const float* bO = (const float*)d_in[10];
    float* out = (float*)d_out;

    __bf16* A  = (__bf16*)d_ws;                                   // 32 MiB
    __bf16* Wt = (__bf16*)((char*)d_ws + (size_t)BROWS * IH * 2); // 16 MiB

    pack_both<<<8192 + 8192, 256, 0, stream>>>(x, hs, Wf, Wi, Wc, Wo, A, Wt);
    lstm_gemm<<<dim3(HDIM / BH, BROWS / BM), 256, 0, stream>>>(A, Wt, cs, bF, bI, bC, bO, out);
}